// Round 1
// baseline (666.288 us; speedup 1.0000x reference)
//
#include <hip/hip_runtime.h>
#include <cstdint>
#include <cstddef>

#define EPI_QKV  0
#define EPI_F32  2
#define EPI_GELU 3

typedef __attribute__((ext_vector_type(8))) short bfrag8;   // 8 bf16 (4 VGPRs)
typedef __attribute__((ext_vector_type(4))) float facc4;    // 4 fp32 acc

__device__ __forceinline__ unsigned short f2b(float x) {
  unsigned int u = __builtin_bit_cast(unsigned int, x);
  u += 0x7FFFu + ((u >> 16) & 1u);   // RNE
  return (unsigned short)(u >> 16);
}

__device__ __forceinline__ void gl2lds16(const unsigned short* g, unsigned short* l) {
  __builtin_amdgcn_global_load_lds(
      (const __attribute__((address_space(1))) unsigned int*)g,
      (__attribute__((address_space(3))) unsigned int*)l, 16, 0, 0);
}

// ---------------- elementwise fp32 -> bf16 ----------------
__global__ __launch_bounds__(256)
void cvt_bf16_kernel(const float* __restrict__ in, unsigned short* __restrict__ out, int n4) {
  const int i = blockIdx.x * 256 + threadIdx.x;
  if (i < n4) {
    const float4 v = ((const float4*)in)[i];
    ushort4 u;
    u.x = f2b(v.x); u.y = f2b(v.y); u.z = f2b(v.z); u.w = f2b(v.w);
    ((ushort4*)out)[i] = u;
  }
}

// ---------------- transpose + convert: in (K x N) fp32 -> out (N x K) bf16 ----------------
__global__ __launch_bounds__(256)
void transpose_cvt(const float* __restrict__ in, unsigned short* __restrict__ out,
                   int K, int N) {
  __shared__ float tile[32][33];
  const int n0 = blockIdx.x * 32;
  const int k0 = blockIdx.y * 32;
  const int tx = threadIdx.x & 31, ty = threadIdx.x >> 5;  // ty 0..7
#pragma unroll
  for (int i = 0; i < 32; i += 8)
    tile[ty + i][tx] = in[(size_t)(k0 + ty + i) * N + n0 + tx];
  __syncthreads();
#pragma unroll
  for (int i = 0; i < 32; i += 8)
    out[(size_t)(n0 + ty + i) * K + k0 + tx] = f2b(tile[tx][ty + i]);
}

// ---------------- GEMM: C = A(MxK) @ Bt(NxK)^T, bf16 MFMA, fused epilogues ----------------
// 128x128 tile, BK=32, 4 waves (2x2), 4x4 16x16x32 MFMA tiles per wave. m97 structure.
template<int EPI>
__global__ __launch_bounds__(256, 2)
void gemm_bt(const unsigned short* __restrict__ A,
             const unsigned short* __restrict__ Bt,
             const float* __restrict__ bias,
             const float* __restrict__ bias2,
             const float* __restrict__ bias3,
             void* __restrict__ out,
             int M, int N, int K) {
  __shared__ unsigned short sA[128 * 32];
  __shared__ unsigned short sB[128 * 32];
  const int tid  = threadIdx.x;
  const int lane = tid & 63;
  const int wave = tid >> 6;
  const int l15  = lane & 15, l4 = lane >> 4;
  const int wr = wave >> 1, wc = wave & 1;
  const long row0 = (long)blockIdx.y * 128;
  const long col0 = (long)blockIdx.x * 128;

  facc4 acc[4][4];
#pragma unroll
  for (int i = 0; i < 4; i++)
#pragma unroll
    for (int j = 0; j < 4; j++) acc[i][j] = (facc4)0.f;

  // staging: pass p covers rows p*64 + tid/4, 8 bf16 per lane, LDS row-major 128x32
  const int srow = tid >> 2;
  const int scol = (tid & 3) * 8;
  const unsigned short* Ap0 = A  + (row0 + srow) * (long)K + scol;
  const unsigned short* Ap1 = Ap0 + 64 * (long)K;
  const unsigned short* Bp0 = Bt + (col0 + srow) * (long)K + scol;
  const unsigned short* Bp1 = Bp0 + 64 * (long)K;
  const int wbase = (tid & ~63) * 8;           // wave-uniform LDS base (elements)
  unsigned short* sA0 = &sA[wbase];
  unsigned short* sA1 = &sA[2048 + wbase];
  unsigned short* sB0 = &sB[wbase];
  unsigned short* sB1 = &sB[2048 + wbase];

  const int aoff = (wr * 64 + l15) * 32 + l4 * 8;
  const int boff = (wc * 64 + l15) * 32 + l4 * 8;

  for (int kt = 0; kt < K; kt += 32) {
    gl2lds16(Ap0 + kt, sA0);
    gl2lds16(Ap1 + kt, sA1);
    gl2lds16(Bp0 + kt, sB0);
    gl2lds16(Bp1 + kt, sB1);
    __syncthreads();
    bfrag8 af[4], bf[4];
#pragma unroll
    for (int i = 0; i < 4; i++) af[i] = *(const bfrag8*)&sA[aoff + i * 512];
#pragma unroll
    for (int j = 0; j < 4; j++) bf[j] = *(const bfrag8*)&sB[boff + j * 512];
#pragma unroll
    for (int i = 0; i < 4; i++)
#pragma unroll
      for (int j = 0; j < 4; j++)
        acc[i][j] = __builtin_amdgcn_mfma_f32_16x16x32_bf16(af[i], bf[j], acc[i][j], 0, 0, 0);
    __syncthreads();
  }

  // epilogue: C element (m, c): m = row0+wr*64+i*16+l4*4+r, c = col0+wc*64+j*16+l15
#pragma unroll
  for (int i = 0; i < 4; i++) {
    const long m0 = row0 + wr * 64 + i * 16 + l4 * 4;
#pragma unroll
    for (int j = 0; j < 4; j++) {
      const long c = col0 + wc * 64 + j * 16 + l15;
      if constexpr (EPI == EPI_QKV) {
        // N==3072: c<1024 -> Q (scaled 1/32), <2048 -> K, else -> V in per-head (d,s) layout
        const long which = c >> 10;
        const long cl = c & 1023;
        unsigned short* oq = (unsigned short*)out;
        if (which == 0) {
          const float bj = bias[cl];
#pragma unroll
          for (int r = 0; r < 4; r++)
            oq[(m0 + r) * 1024 + cl] = f2b((acc[i][j][r] + bj) * 0.03125f);
        } else if (which == 1) {
          const float bj = bias2[cl];
#pragma unroll
          for (int r = 0; r < 4; r++)
            (oq + 4194304)[(m0 + r) * 1024 + cl] = f2b(acc[i][j][r] + bj);
        } else {
          const float bj = bias3[cl];
          const long cc = cl >> 6, d = cl & 63;
#pragma unroll
          for (int r = 0; r < 4; r++) {
            const long m = m0 + r;
            const long nbb = m >> 10, rr = m & 1023;
            const long h = rr >> 6, rhi = rr & 63;
            const long s = rhi * 16 + cc;           // sequence index in the head view
            (oq + 8388608)[((nbb * 16 + h) * 64 + d) * 1024 + s] = f2b(acc[i][j][r] + bj);
          }
        }
      } else if constexpr (EPI == EPI_F32) {
        const float bj = bias[c];
        float* of = (float*)out;
#pragma unroll
        for (int r = 0; r < 4; r++) of[(m0 + r) * (long)N + c] = acc[i][j][r] + bj;
      } else {  // EPI_GELU -> bf16
        const float bj = bias[c];
        unsigned short* ob = (unsigned short*)out;
#pragma unroll
        for (int r = 0; r < 4; r++) {
          const float t = acc[i][j][r] + bj;
          ob[(m0 + r) * (long)N + c] = f2b(0.5f * t * (1.f + erff(t * 0.70710678f)));
        }
      }
    }
  }
}

// ---------------- fused attention (softmax over HEADS at each (t,s)) ----------------
// grid (32 t-tiles, 4 batches); 4 waves, wave w -> heads 4w..4w+3; Tt=32, s-chunks of 32.
// Qb/Kb: per-head contiguous (s,d) 1024x64 bf16 (Q pre-scaled 1/32). Vt: per-head (d,s) 64x1024.
__global__ __launch_bounds__(256, 1)
void attn_kernel(const unsigned short* __restrict__ Qb,
                 const unsigned short* __restrict__ Kb,
                 const unsigned short* __restrict__ Vt,
                 unsigned short* __restrict__ Ob) {
  const int tt = blockIdx.x;       // t-tile
  const int nb = blockIdx.y;       // batch
  const int tid = threadIdx.x, lane = tid & 63, w = tid >> 6;
  const int l15 = lane & 15, l4 = lane >> 4;
  const int t0 = tt * 32;

  __shared__ float red[32][32][4];              // head-sum exchange (16KB)
  __shared__ unsigned short abuf[4][4][32][40]; // attn bf16, [wave][head][t][s pad40] (40KB)

  // persistent Q A-frags: [head][mt][ks]
  bfrag8 qf[4][2][2];
#pragma unroll
  for (int hh = 0; hh < 4; hh++) {
    const unsigned short* qh = Qb + ((size_t)(nb * 16 + w * 4 + hh) << 16);
#pragma unroll
    for (int mt = 0; mt < 2; mt++)
#pragma unroll
      for (int ks = 0; ks < 2; ks++)
        qf[hh][mt][ks] = *(const bfrag8*)(qh + (t0 + mt * 16 + l15) * 64 + ks * 32 + l4 * 8);
  }

  facc4 oacc[4][2][4];
#pragma unroll
  for (int hh = 0; hh < 4; hh++)
#pragma unroll
    for (int mt = 0; mt < 2; mt++)
#pragma unroll
      for (int nt = 0; nt < 4; nt++) oacc[hh][mt][nt] = (facc4)0.f;

  for (int s0 = 0; s0 < 1024; s0 += 32) {
    // scores = (q/32) @ k^T  (already scaled)
    facc4 sacc[4][2][2];
#pragma unroll
    for (int hh = 0; hh < 4; hh++)
#pragma unroll
      for (int mt = 0; mt < 2; mt++)
#pragma unroll
        for (int nt = 0; nt < 2; nt++) sacc[hh][mt][nt] = (facc4)0.f;
#pragma unroll
    for (int hh = 0; hh < 4; hh++) {
      const unsigned short* kh = Kb + ((size_t)(nb * 16 + w * 4 + hh) << 16);
#pragma unroll
      for (int nt = 0; nt < 2; nt++)
#pragma unroll
        for (int ks = 0; ks < 2; ks++) {
          const bfrag8 kf = *(const bfrag8*)(kh + (s0 + nt * 16 + l15) * 64 + ks * 32 + l4 * 8);
#pragma unroll
          for (int mt = 0; mt < 2; mt++)
            sacc[hh][mt][nt] =
                __builtin_amdgcn_mfma_f32_16x16x32_bf16(qf[hh][mt][ks], kf, sacc[hh][mt][nt], 0, 0, 0);
        }
    }
    // exp in place (|scores| small -> no max subtraction needed), local sum over wave's 4 heads
    float lsum[2][2][4];
#pragma unroll
    for (int mt = 0; mt < 2; mt++)
#pragma unroll
      for (int nt = 0; nt < 2; nt++)
#pragma unroll
        for (int r = 0; r < 4; r++) {
          float s = 0.f;
#pragma unroll
          for (int hh = 0; hh < 4; hh++) {
            const float e = __expf(sacc[hh][mt][nt][r]);
            sacc[hh][mt][nt][r] = e;
            s += e;
          }
          lsum[mt][nt][r] = s;
        }
    __syncthreads();   // protect red reads of previous chunk
#pragma unroll
    for (int mt = 0; mt < 2; mt++)
#pragma unroll
      for (int nt = 0; nt < 2; nt++)
#pragma unroll
        for (int r = 0; r < 4; r++)
          red[mt * 16 + l4 * 4 + r][nt * 16 + l15][w] = lsum[mt][nt][r];
    __syncthreads();
    float rinv[2][2][4];
#pragma unroll
    for (int mt = 0; mt < 2; mt++)
#pragma unroll
      for (int nt = 0; nt < 2; nt++)
#pragma unroll
        for (int r = 0; r < 4; r++) {
          const float4 v4 = *(const float4*)&red[mt * 16 + l4 * 4 + r][nt * 16 + l15][0];
          rinv[mt][nt][r] = 1.f / (v4.x + v4.y + v4.z + v4.w);
        }
    // attn -> bf16 -> wave-private LDS (C-layout write, A-layout read)
#pragma unroll
    for (int hh = 0; hh < 4; hh++)
#pragma unroll
      for (int mt = 0; mt < 2; mt++)
#pragma unroll
        for (int nt = 0; nt < 2; nt++)
#pragma unroll
          for (int r = 0; r < 4; r++)
            abuf[w][hh][mt * 16 + l4 * 4 + r][nt * 16 + l15] =
                f2b(sacc[hh][mt][nt][r] * rinv[mt][nt][r]);
    // o += attn @ v   (B-frags contiguous thanks to Vt (d,s) layout)
#pragma unroll
    for (int hh = 0; hh < 4; hh++) {
      const unsigned short* vh = Vt + ((size_t)(nb * 16 + w * 4 + hh) << 16);
      bfrag8 af[2];
#pragma unroll
      for (int mt = 0; mt < 2; mt++)
        af[mt] = *(const bfrag8*)&abuf[w][hh][mt * 16 + l15][l4 * 8];
#pragma unroll
      for (int nt = 0; nt < 4; nt++) {
        const bfrag8 vf = *(const bfrag8*)(vh + (size_t)(nt * 16 + l15) * 1024 + s0 + l4 * 8);
#pragma unroll
        for (int mt = 0; mt < 2; mt++)
          oacc[hh][mt][nt] =
              __builtin_amdgcn_mfma_f32_16x16x32_bf16(af[mt], vf, oacc[hh][mt][nt], 0, 0, 0);
      }
    }
  }
  // write O back through the inverse view: Omat[n][h*64 + t/16][(t%16)*64 + d]
#pragma unroll
  for (int hh = 0; hh < 4; hh++) {
    const int h = w * 4 + hh;
#pragma unroll
    for (int mt = 0; mt < 2; mt++)
#pragma unroll
      for (int nt = 0; nt < 4; nt++)
#pragma unroll
        for (int r = 0; r < 4; r++) {
          const int t = t0 + mt * 16 + l4 * 4 + r;
          const int d = nt * 16 + l15;
          const int rowp = h * 64 + (t >> 4);
          const int colp = (t & 15) * 64 + d;
          Ob[((size_t)nb << 20) + (size_t)rowp * 1024 + colp] = f2b(oacc[hh][mt][nt][r]);
        }
  }
}

// ---------------- LayerNorm with fused residual: out = LN(a+b)*g + be ----------------
__global__ __launch_bounds__(256)
void ln_kernel(const float* __restrict__ a, const float* __restrict__ b,
               const float* __restrict__ g, const float* __restrict__ be,
               float* __restrict__ outf, unsigned short* __restrict__ outb) {
  const int row = blockIdx.x, tid = threadIdx.x;
  const float4 va = ((const float4*)(a + (size_t)row * 1024))[tid];
  const float4 vb = ((const float4*)(b + (size_t)row * 1024))[tid];
  float t0 = va.x + vb.x, t1 = va.y + vb.y, t2 = va.z + vb.z, t3 = va.w + vb.w;
  float s = t0 + t1 + t2 + t3;
  float q = t0 * t0 + t1 * t1 + t2 * t2 + t3 * t3;
#pragma unroll
  for (int off = 32; off > 0; off >>= 1) {
    s += __shfl_down(s, off, 64);
    q += __shfl_down(q, off, 64);
  }
  __shared__ float rs_[4], rq_[4];
  if ((tid & 63) == 0) { rs_[tid >> 6] = s; rq_[tid >> 6] = q; }
  __syncthreads();
  const float S = rs_[0] + rs_[1] + rs_[2] + rs_[3];
  const float Q = rq_[0] + rq_[1] + rq_[2] + rq_[3];
  const float mean = S * (1.f / 1024.f);
  const float var  = Q * (1.f / 1024.f) - mean * mean;
  const float rstd = rsqrtf(var + 1e-5f);
  const float4 vg  = ((const float4*)g)[tid];
  const float4 vbe = ((const float4*)be)[tid];
  float o0 = (t0 - mean) * rstd * vg.x + vbe.x;
  float o1 = (t1 - mean) * rstd * vg.y + vbe.y;
  float o2 = (t2 - mean) * rstd * vg.z + vbe.z;
  float o3 = (t3 - mean) * rstd * vg.w + vbe.w;
  ((float4*)(outf + (size_t)row * 1024))[tid] = make_float4(o0, o1, o2, o3);
  if (outb != nullptr) {
    ushort4 u;
    u.x = f2b(o0); u.y = f2b(o1); u.z = f2b(o2); u.w = f2b(o3);
    ((ushort4*)(outb + (size_t)row * 1024))[tid] = u;
  }
}

// ---------------- launch ----------------
extern "C" void kernel_launch(void* const* d_in, const int* in_sizes, int n_in,
                              void* d_out, int out_size, void* d_ws, size_t ws_size,
                              hipStream_t stream) {
  const float* x  = (const float*)d_in[0];
  const float* Wq = (const float*)d_in[1];
  const float* bq = (const float*)d_in[2];
  const float* Wk = (const float*)d_in[3];
  const float* bk = (const float*)d_in[4];
  const float* Wv = (const float*)d_in[5];
  const float* bv = (const float*)d_in[6];
  const float* Wo = (const float*)d_in[7];
  const float* bo = (const float*)d_in[8];
  const float* g1 = (const float*)d_in[9];
  const float* b1 = (const float*)d_in[10];
  const float* W1 = (const float*)d_in[11];
  const float* c1 = (const float*)d_in[12];
  const float* W2 = (const float*)d_in[13];
  const float* c2 = (const float*)d_in[14];
  const float* g2 = (const float*)d_in[15];
  const float* b2 = (const float*)d_in[16];
  float* out = (float*)d_out;

  char* ws = (char*)d_ws;
  unsigned short* XB  = (unsigned short*)(ws);              // 8MB  x bf16
  unsigned short* WQT = (unsigned short*)(ws + 8388608);    // 2MB  (WQT/WKT/WVT contiguous!)
  unsigned short* WKT = (unsigned short*)(ws + 10485760);   // 2MB
  unsigned short* WVT = (unsigned short*)(ws + 12582912);   // 2MB
  unsigned short* WOT = (unsigned short*)(ws + 14680064);   // 2MB
  unsigned short* W1T = (unsigned short*)(ws + 16777216);   // 8MB
  unsigned short* W2T = (unsigned short*)(ws + 25165824);   // 8MB
  float*          X1  = (float*)(ws + 33554432);            // 16MB
  unsigned short* X1B = (unsigned short*)(ws + 50331648);   // 8MB
  char* RB = ws + 58720256;                                 // 48MB union region
  unsigned short* QB  = (unsigned short*)(RB);              // 8MB
  unsigned short* KB  = (unsigned short*)(RB + 8388608);    // 8MB
  unsigned short* VT  = (unsigned short*)(RB + 16777216);   // 8MB
  unsigned short* OB  = (unsigned short*)(RB + 25165824);   // 8MB
  float*          OWO = (float*)(RB + 33554432);            // 16MB
  unsigned short* H1B = (unsigned short*)(RB);              // 32MB (aliases QB..OB, FFN phase)
  float*          FF  = (float*)(RB + 33554432);            // 16MB (aliases OWO)

  const dim3 tb(256);
  // convert + transpose weights
  cvt_bf16_kernel<<<dim3(4096), tb, 0, stream>>>(x, XB, 1048576);
  transpose_cvt<<<dim3(32, 32),  tb, 0, stream>>>(Wq, WQT, 1024, 1024);
  transpose_cvt<<<dim3(32, 32),  tb, 0, stream>>>(Wk, WKT, 1024, 1024);
  transpose_cvt<<<dim3(32, 32),  tb, 0, stream>>>(Wv, WVT, 1024, 1024);
  transpose_cvt<<<dim3(32, 32),  tb, 0, stream>>>(Wo, WOT, 1024, 1024);
  transpose_cvt<<<dim3(128, 32), tb, 0, stream>>>(W1, W1T, 1024, 4096);
  transpose_cvt<<<dim3(32, 128), tb, 0, stream>>>(W2, W2T, 4096, 1024);
  // fused QKV projection (N=3072), epilogue scatters Q(scaled), K, V(transposed per head)
  gemm_bt<EPI_QKV><<<dim3(24, 32), tb, 0, stream>>>(XB, WQT, bq, bk, bv, (void*)QB, 4096, 3072, 1024);
  // fused attention with head-axis softmax
  attn_kernel<<<dim3(32, 4), tb, 0, stream>>>(QB, KB, VT, OB);
  // O projection (+bo), fp32
  gemm_bt<EPI_F32><<<dim3(8, 32), tb, 0, stream>>>(OB, WOT, bo, nullptr, nullptr, (void*)OWO, 4096, 1024, 1024);
  // LN1 with residual x -> X1 (fp32) + X1B (bf16)
  ln_kernel<<<dim3(4096), tb, 0, stream>>>(OWO, x, g1, b1, X1, X1B);
  // FFN1 + exact GELU -> bf16
  gemm_bt<EPI_GELU><<<dim3(32, 32), tb, 0, stream>>>(X1B, W1T, c1, nullptr, nullptr, (void*)H1B, 4096, 4096, 1024);
  // FFN2 (+c2) -> fp32
  gemm_bt<EPI_F32><<<dim3(8, 32), tb, 0, stream>>>(H1B, W2T, c2, nullptr, nullptr, (void*)FF, 4096, 1024, 4096);
  // LN2 with residual X1 -> out (fp32)
  ln_kernel<<<dim3(4096), tb, 0, stream>>>(FF, X1, g2, b2, out, (unsigned short*)nullptr);
}

// Round 2
// 499.004 us; speedup vs baseline: 1.3352x; 1.3352x over previous
//
#include <hip/hip_runtime.h>
#include <cstdint>
#include <cstddef>

#define EPI_QKV  0
#define EPI_F32  2
#define EPI_GELU 3

typedef __attribute__((ext_vector_type(8))) short bfrag8;   // 8 bf16 (4 VGPRs)
typedef __attribute__((ext_vector_type(4))) float facc4;    // 4 fp32 acc

__device__ __forceinline__ unsigned short f2b(float x) {
  unsigned int u = __builtin_bit_cast(unsigned int, x);
  u += 0x7FFFu + ((u >> 16) & 1u);   // RNE
  return (unsigned short)(u >> 16);
}

__device__ __forceinline__ void gl2lds16(const unsigned short* g, unsigned short* l) {
  __builtin_amdgcn_global_load_lds(
      (const __attribute__((address_space(1))) unsigned int*)g,
      (__attribute__((address_space(3))) unsigned int*)l, 16, 0, 0);
}

// ---------------- elementwise fp32 -> bf16 ----------------
__global__ __launch_bounds__(256)
void cvt_bf16_kernel(const float* __restrict__ in, unsigned short* __restrict__ out, int n4) {
  const int i = blockIdx.x * 256 + threadIdx.x;
  if (i < n4) {
    const float4 v = ((const float4*)in)[i];
    ushort4 u;
    u.x = f2b(v.x); u.y = f2b(v.y); u.z = f2b(v.z); u.w = f2b(v.w);
    ((ushort4*)out)[i] = u;
  }
}

// ---------------- transpose + convert: in (K x N) fp32 -> out (N x K) bf16 ----------------
__global__ __launch_bounds__(256)
void transpose_cvt(const float* __restrict__ in, unsigned short* __restrict__ out,
                   int K, int N) {
  __shared__ float tile[32][33];
  const int n0 = blockIdx.x * 32;
  const int k0 = blockIdx.y * 32;
  const int tx = threadIdx.x & 31, ty = threadIdx.x >> 5;  // ty 0..7
#pragma unroll
  for (int i = 0; i < 32; i += 8)
    tile[ty + i][tx] = in[(size_t)(k0 + ty + i) * N + n0 + tx];
  __syncthreads();
#pragma unroll
  for (int i = 0; i < 32; i += 8)
    out[(size_t)(n0 + ty + i) * K + k0 + tx] = f2b(tile[tx][ty + i]);
}

// ---------------- GEMM: C = A(MxK) @ Bt(NxK)^T, bf16 MFMA, fused epilogues ----------------
// 128x128 tile, BK=32, 4 waves (2x2), 4x4 16x16x32 MFMA tiles per wave. m97 structure.
template<int EPI>
__global__ __launch_bounds__(256, 2)
void gemm_bt(const unsigned short* __restrict__ A,
             const unsigned short* __restrict__ Bt,
             const float* __restrict__ bias,
             const float* __restrict__ bias2,
             const float* __restrict__ bias3,
             void* __restrict__ out,
             int M, int N, int K) {
  __shared__ unsigned short sA[128 * 32];
  __shared__ unsigned short sB[128 * 32];
  const int tid  = threadIdx.x;
  const int lane = tid & 63;
  const int wave = tid >> 6;
  const int l15  = lane & 15, l4 = lane >> 4;
  const int wr = wave >> 1, wc = wave & 1;
  const long row0 = (long)blockIdx.y * 128;
  const long col0 = (long)blockIdx.x * 128;

  facc4 acc[4][4];
#pragma unroll
  for (int i = 0; i < 4; i++)
#pragma unroll
    for (int j = 0; j < 4; j++) acc[i][j] = (facc4)0.f;

  const int srow = tid >> 2;
  const int scol = (tid & 3) * 8;
  const unsigned short* Ap0 = A  + (row0 + srow) * (long)K + scol;
  const unsigned short* Ap1 = Ap0 + 64 * (long)K;
  const unsigned short* Bp0 = Bt + (col0 + srow) * (long)K + scol;
  const unsigned short* Bp1 = Bp0 + 64 * (long)K;
  const int wbase = (tid & ~63) * 8;           // wave-uniform LDS base (elements)
  unsigned short* sA0 = &sA[wbase];
  unsigned short* sA1 = &sA[2048 + wbase];
  unsigned short* sB0 = &sB[wbase];
  unsigned short* sB1 = &sB[2048 + wbase];

  const int aoff = (wr * 64 + l15) * 32 + l4 * 8;
  const int boff = (wc * 64 + l15) * 32 + l4 * 8;

  for (int kt = 0; kt < K; kt += 32) {
    gl2lds16(Ap0 + kt, sA0);
    gl2lds16(Ap1 + kt, sA1);
    gl2lds16(Bp0 + kt, sB0);
    gl2lds16(Bp1 + kt, sB1);
    __syncthreads();
    bfrag8 af[4], bf[4];
#pragma unroll
    for (int i = 0; i < 4; i++) af[i] = *(const bfrag8*)&sA[aoff + i * 512];
#pragma unroll
    for (int j = 0; j < 4; j++) bf[j] = *(const bfrag8*)&sB[boff + j * 512];
#pragma unroll
    for (int i = 0; i < 4; i++)
#pragma unroll
      for (int j = 0; j < 4; j++)
        acc[i][j] = __builtin_amdgcn_mfma_f32_16x16x32_bf16(af[i], bf[j], acc[i][j], 0, 0, 0);
    __syncthreads();
  }

#pragma unroll
  for (int i = 0; i < 4; i++) {
    const long m0 = row0 + wr * 64 + i * 16 + l4 * 4;
#pragma unroll
    for (int j = 0; j < 4; j++) {
      const long c = col0 + wc * 64 + j * 16 + l15;
      if constexpr (EPI == EPI_QKV) {
        const long which = c >> 10;
        const long cl = c & 1023;
        unsigned short* oq = (unsigned short*)out;
        if (which == 0) {
          const float bj = bias[cl];
#pragma unroll
          for (int r = 0; r < 4; r++)
            oq[(m0 + r) * 1024 + cl] = f2b((acc[i][j][r] + bj) * 0.03125f);
        } else if (which == 1) {
          const float bj = bias2[cl];
#pragma unroll
          for (int r = 0; r < 4; r++)
            (oq + 4194304)[(m0 + r) * 1024 + cl] = f2b(acc[i][j][r] + bj);
        } else {
          const float bj = bias3[cl];
          const long cc = cl >> 6, d = cl & 63;
#pragma unroll
          for (int r = 0; r < 4; r++) {
            const long m = m0 + r;
            const long nbb = m >> 10, rr = m & 1023;
            const long h = rr >> 6, rhi = rr & 63;
            const long s = rhi * 16 + cc;
            (oq + 8388608)[((nbb * 16 + h) * 64 + d) * 1024 + s] = f2b(acc[i][j][r] + bj);
          }
        }
      } else if constexpr (EPI == EPI_F32) {
        const float bj = bias[c];
        float* of = (float*)out;
#pragma unroll
        for (int r = 0; r < 4; r++) of[(m0 + r) * (long)N + c] = acc[i][j][r] + bj;
      } else {  // EPI_GELU -> bf16
        const float bj = bias[c];
        unsigned short* ob = (unsigned short*)out;
#pragma unroll
        for (int r = 0; r < 4; r++) {
          const float t = acc[i][j][r] + bj;
          ob[(m0 + r) * (long)N + c] = f2b(0.5f * t * (1.f + erff(t * 0.70710678f)));
        }
      }
    }
  }
}

// ---------------- fused attention v2 (softmax over HEADS at each (t,s)) ----------------
// grid (64 t-tiles, 4 batches, 2 s-splits); 8 waves x 2 heads; t-tile 16; s-chunks of 32.
// Qb/Kb: per-head (s,d) 1024x64 bf16 (Q pre-scaled 1/32). Vt: per-head (d,s) 64x1024.
// Writes fp32 partial O (inverse-view layout) to PA (split 0) / PB (split 1).
__global__ __launch_bounds__(512, 4)
void attn_kernel(const unsigned short* __restrict__ Qb,
                 const unsigned short* __restrict__ Kb,
                 const unsigned short* __restrict__ Vt,
                 float* __restrict__ PA, float* __restrict__ PB) {
  const int tile = blockIdx.x;     // t-tile (16 rows)
  const int nb = blockIdx.y;       // batch
  const int sp = blockIdx.z;       // s-split
  const int tid = threadIdx.x, lane = tid & 63, w = tid >> 6;   // w 0..7
  const int l15 = lane & 15, l4 = lane >> 4;
  const int t0 = tile * 16;

  // red: addr = w*576 + t*36 + s  (t-stride 36 == 4 mod 32 -> 2-way banks, free)
  __shared__ float red[8 * 576];                        // 18 KB
  __shared__ __align__(16) unsigned short abuf[8][2][16][40];  // 20 KB, wave-private

  const unsigned short* qh[2];
  const unsigned short* kh[2];
  const unsigned short* vh[2];
#pragma unroll
  for (int hh = 0; hh < 2; hh++) {
    const size_t hb = (size_t)(nb * 16 + w * 2 + hh) << 16;
    qh[hh] = Qb + hb; kh[hh] = Kb + hb; vh[hh] = Vt + hb;
  }

  facc4 oacc[2][4];
#pragma unroll
  for (int hh = 0; hh < 2; hh++)
#pragma unroll
    for (int nt = 0; nt < 4; nt++) oacc[hh][nt] = (facc4)0.f;

  const int sEnd = sp * 512 + 512;
  for (int s0 = sp * 512; s0 < sEnd; s0 += 32) {
    // ---- scores = (q/32) @ k^T over this 16t x 32s chunk, 2 heads ----
    facc4 sacc[2][2];
#pragma unroll
    for (int hh = 0; hh < 2; hh++)
#pragma unroll
      for (int nt = 0; nt < 2; nt++) sacc[hh][nt] = (facc4)0.f;
#pragma unroll
    for (int hh = 0; hh < 2; hh++) {
#pragma unroll
      for (int ks = 0; ks < 2; ks++) {
        const bfrag8 qf = *(const bfrag8*)(qh[hh] + (t0 + l15) * 64 + ks * 32 + l4 * 8);
#pragma unroll
        for (int nt = 0; nt < 2; nt++) {
          const bfrag8 kf = *(const bfrag8*)(kh[hh] + (s0 + nt * 16 + l15) * 64 + ks * 32 + l4 * 8);
          sacc[hh][nt] = __builtin_amdgcn_mfma_f32_16x16x32_bf16(qf, kf, sacc[hh][nt], 0, 0, 0);
        }
      }
    }
    // ---- exp in place; local sum over this wave's 2 heads ----
    float lsum[2][4];
#pragma unroll
    for (int nt = 0; nt < 2; nt++)
#pragma unroll
      for (int r = 0; r < 4; r++) {
        const float e0 = __expf(sacc[0][nt][r]);
        const float e1 = __expf(sacc[1][nt][r]);
        sacc[0][nt][r] = e0; sacc[1][nt][r] = e1;
        lsum[nt][r] = e0 + e1;
      }
    __syncthreads();   // previous iteration's red reads are done
#pragma unroll
    for (int nt = 0; nt < 2; nt++)
#pragma unroll
      for (int r = 0; r < 4; r++)
        red[w * 576 + (l4 * 4 + r) * 36 + nt * 16 + l15] = lsum[nt][r];
    __syncthreads();
    // ---- head-sum over all 8 waves (16 heads), reciprocal ----
    float rinv[2][4];
#pragma unroll
    for (int nt = 0; nt < 2; nt++)
#pragma unroll
      for (int r = 0; r < 4; r++) {
        const int o = (l4 * 4 + r) * 36 + nt * 16 + l15;
        float s = 0.f;
#pragma unroll
        for (int ww = 0; ww < 8; ww++) s += red[ww * 576 + o];
        rinv[nt][r] = 1.f / s;
      }
    // ---- normalize -> bf16 -> wave-private LDS (C-layout write, A-layout read) ----
#pragma unroll
    for (int hh = 0; hh < 2; hh++)
#pragma unroll
      for (int nt = 0; nt < 2; nt++)
#pragma unroll
        for (int r = 0; r < 4; r++)
          abuf[w][hh][l4 * 4 + r][nt * 16 + l15] = f2b(sacc[hh][nt][r] * rinv[nt][r]);
    // ---- o += attn @ v ----
#pragma unroll
    for (int hh = 0; hh < 2; hh++) {
      const bfrag8 af = *(const bfrag8*)&abuf[w][hh][l15][l4 * 8];
#pragma unroll
      for (int nt = 0; nt < 4; nt++) {
        const bfrag8 vf = *(const bfrag8*)(vh[hh] + (size_t)(nt * 16 + l15) * 1024 + s0 + l4 * 8);
        oacc[hh][nt] = __builtin_amdgcn_mfma_f32_16x16x32_bf16(af, vf, oacc[hh][nt], 0, 0, 0);
      }
    }
  }
  // ---- write fp32 partial through the inverse view: row = h*64 + tile, col = (t&15)*64 + d
  float* P = (sp == 0) ? PA : PB;
#pragma unroll
  for (int hh = 0; hh < 2; hh++) {
    const int h = w * 2 + hh;
    const size_t rb = ((size_t)nb * 1024 + h * 64 + tile) * 1024;
#pragma unroll
    for (int nt = 0; nt < 4; nt++)
#pragma unroll
      for (int r = 0; r < 4; r++)
        P[rb + (size_t)(l4 * 4 + r) * 64 + nt * 16 + l15] = oacc[hh][nt][r];
  }
}

// ---------------- partial-O reduce: OB = bf16(PA + PB) ----------------
__global__ __launch_bounds__(256)
void reduce_o(const float* __restrict__ PA, const float* __restrict__ PB,
              unsigned short* __restrict__ OB, int n4) {
  const int i = blockIdx.x * 256 + threadIdx.x;
  if (i < n4) {
    const float4 a = ((const float4*)PA)[i];
    const float4 b = ((const float4*)PB)[i];
    ushort4 u;
    u.x = f2b(a.x + b.x); u.y = f2b(a.y + b.y);
    u.z = f2b(a.z + b.z); u.w = f2b(a.w + b.w);
    ((ushort4*)OB)[i] = u;
  }
}

// ---------------- LayerNorm with fused residual: out = LN(a+b)*g + be ----------------
__global__ __launch_bounds__(256)
void ln_kernel(const float* __restrict__ a, const float* __restrict__ b,
               const float* __restrict__ g, const float* __restrict__ be,
               float* __restrict__ outf, unsigned short* __restrict__ outb) {
  const int row = blockIdx.x, tid = threadIdx.x;
  const float4 va = ((const float4*)(a + (size_t)row * 1024))[tid];
  const float4 vb = ((const float4*)(b + (size_t)row * 1024))[tid];
  float t0 = va.x + vb.x, t1 = va.y + vb.y, t2 = va.z + vb.z, t3 = va.w + vb.w;
  float s = t0 + t1 + t2 + t3;
  float q = t0 * t0 + t1 * t1 + t2 * t2 + t3 * t3;
#pragma unroll
  for (int off = 32; off > 0; off >>= 1) {
    s += __shfl_down(s, off, 64);
    q += __shfl_down(q, off, 64);
  }
  __shared__ float rs_[4], rq_[4];
  if ((tid & 63) == 0) { rs_[tid >> 6] = s; rq_[tid >> 6] = q; }
  __syncthreads();
  const float S = rs_[0] + rs_[1] + rs_[2] + rs_[3];
  const float Q = rq_[0] + rq_[1] + rq_[2] + rq_[3];
  const float mean = S * (1.f / 1024.f);
  const float var  = Q * (1.f / 1024.f) - mean * mean;
  const float rstd = rsqrtf(var + 1e-5f);
  const float4 vg  = ((const float4*)g)[tid];
  const float4 vbe = ((const float4*)be)[tid];
  float o0 = (t0 - mean) * rstd * vg.x + vbe.x;
  float o1 = (t1 - mean) * rstd * vg.y + vbe.y;
  float o2 = (t2 - mean) * rstd * vg.z + vbe.z;
  float o3 = (t3 - mean) * rstd * vg.w + vbe.w;
  ((float4*)(outf + (size_t)row * 1024))[tid] = make_float4(o0, o1, o2, o3);
  if (outb != nullptr) {
    ushort4 u;
    u.x = f2b(o0); u.y = f2b(o1); u.z = f2b(o2); u.w = f2b(o3);
    ((ushort4*)(outb + (size_t)row * 1024))[tid] = u;
  }
}

// ---------------- launch ----------------
extern "C" void kernel_launch(void* const* d_in, const int* in_sizes, int n_in,
                              void* d_out, int out_size, void* d_ws, size_t ws_size,
                              hipStream_t stream) {
  const float* x  = (const float*)d_in[0];
  const float* Wq = (const float*)d_in[1];
  const float* bq = (const float*)d_in[2];
  const float* Wk = (const float*)d_in[3];
  const float* bk = (const float*)d_in[4];
  const float* Wv = (const float*)d_in[5];
  const float* bv = (const float*)d_in[6];
  const float* Wo = (const float*)d_in[7];
  const float* bo = (const float*)d_in[8];
  const float* g1 = (const float*)d_in[9];
  const float* b1 = (const float*)d_in[10];
  const float* W1 = (const float*)d_in[11];
  const float* c1 = (const float*)d_in[12];
  const float* W2 = (const float*)d_in[13];
  const float* c2 = (const float*)d_in[14];
  const float* g2 = (const float*)d_in[15];
  const float* b2 = (const float*)d_in[16];
  float* out = (float*)d_out;

  char* ws = (char*)d_ws;
  unsigned short* XB  = (unsigned short*)(ws);              // 8MB  x bf16
  unsigned short* WQT = (unsigned short*)(ws + 8388608);    // 2MB
  unsigned short* WKT = (unsigned short*)(ws + 10485760);   // 2MB
  unsigned short* WVT = (unsigned short*)(ws + 12582912);   // 2MB
  unsigned short* WOT = (unsigned short*)(ws + 14680064);   // 2MB
  unsigned short* W1T = (unsigned short*)(ws + 16777216);   // 8MB
  unsigned short* W2T = (unsigned short*)(ws + 25165824);   // 8MB
  float*          X1  = (float*)(ws + 33554432);            // 16MB (attn-phase: partial B)
  unsigned short* X1B = (unsigned short*)(ws + 50331648);   // 8MB
  char* RB = ws + 58720256;                                 // 48MB union region
  unsigned short* QB  = (unsigned short*)(RB);              // 8MB
  unsigned short* KB  = (unsigned short*)(RB + 8388608);    // 8MB
  unsigned short* VT  = (unsigned short*)(RB + 16777216);   // 8MB
  unsigned short* OB  = (unsigned short*)(RB + 25165824);   // 8MB
  float*          OWO = (float*)(RB + 33554432);            // 16MB (attn-phase: partial A)
  unsigned short* H1B = (unsigned short*)(RB);              // 32MB (aliases QB..OB, FFN phase)
  float*          FF  = (float*)(RB + 33554432);            // 16MB (aliases OWO)
  float*          PA  = OWO;                                // s-split 0 partial
  float*          PB  = X1;                                 // s-split 1 partial

  const dim3 tb(256);
  cvt_bf16_kernel<<<dim3(4096), tb, 0, stream>>>(x, XB, 1048576);
  transpose_cvt<<<dim3(32, 32),  tb, 0, stream>>>(Wq, WQT, 1024, 1024);
  transpose_cvt<<<dim3(32, 32),  tb, 0, stream>>>(Wk, WKT, 1024, 1024);
  transpose_cvt<<<dim3(32, 32),  tb, 0, stream>>>(Wv, WVT, 1024, 1024);
  transpose_cvt<<<dim3(32, 32),  tb, 0, stream>>>(Wo, WOT, 1024, 1024);
  transpose_cvt<<<dim3(128, 32), tb, 0, stream>>>(W1, W1T, 1024, 4096);
  transpose_cvt<<<dim3(32, 128), tb, 0, stream>>>(W2, W2T, 4096, 1024);
  gemm_bt<EPI_QKV><<<dim3(24, 32), tb, 0, stream>>>(XB, WQT, bq, bk, bv, (void*)QB, 4096, 3072, 1024);
  attn_kernel<<<dim3(64, 4, 2), dim3(512), 0, stream>>>(QB, KB, VT, PA, PB);
  reduce_o<<<dim3(4096), tb, 0, stream>>>(PA, PB, OB, 1048576);
  gemm_bt<EPI_F32><<<dim3(8, 32), tb, 0, stream>>>(OB, WOT, bo, nullptr, nullptr, (void*)OWO, 4096, 1024, 1024);
  ln_kernel<<<dim3(4096), tb, 0, stream>>>(OWO, x, g1, b1, X1, X1B);
  gemm_bt<EPI_GELU><<<dim3(32, 32), tb, 0, stream>>>(X1B, W1T, c1, nullptr, nullptr, (void*)H1B, 4096, 4096, 1024);
  gemm_bt<EPI_F32><<<dim3(8, 32), tb, 0, stream>>>(H1B, W2T, c2, nullptr, nullptr, (void*)FF, 4096, 1024, 4096);
  ln_kernel<<<dim3(4096), tb, 0, stream>>>(FF, X1, g2, b2, out, (unsigned short*)nullptr);
}